// Round 6
// baseline (517.420 us; speedup 1.0000x reference)
//
#include <hip/hip_runtime.h>

// dv = (-v + segment_sum(w * relu(v[src]) * tp[ntype[src]], dst) + stim + Vrest) / tau
// N_NODES = 500000, N_EDGES = 16000000. edge_index flat: src=[0,E), dst=[E,2E).
//
// R1: agent-scope fp32 atomics -> memory-side RMW wall (~20G/s) -> 785us.
// R2: counting sort, direct 4B random writes -> 7x write amp -> 489us scatter.
// R3: workgroup-scope atomics == agent-scope on gfx950 (no relocation).
// R4: LDS-staged bucket sort + coalesced bursts -> 241us scatter @ 19% occ.
// R5: 1024-thr scatter (32 waves/CU) + prefix-derived local hist -> 188us
//     scatter, but hist+scan+accum scaffolding = ~286us of the 474 total.
// R6 (this): drop the GLOBAL sort. Each scatter block owns a fixed 16384-record
//     slice of 'sorted': local hist (dst chunk read 2x, 2nd hit L2), local scan,
//     LDS binning, ONE dense contiguous uint4 copy-out + local-prefix row.
//     hist/scan_blocks/scan_buckets kernels deleted. Accum walks per-block
//     segments via the lpref matrix (3.8MB, L2/L3-resident).

#define BSHIFT 9
#define BSIZE  512               // nodes per bucket
#define NBMAX  1024              // > nb = ceil(500000/512) = 977
#define GPB    4096              // int4 groups per scatter block = 16384 edges
#define EPB    (GPB * 4)

// ---------------- main path ----------------

__global__ void pre_g_kernel(const float* __restrict__ v,
                             const int* __restrict__ ntype,
                             const float* __restrict__ tp,
                             float* __restrict__ g, int n) {
    int i = blockIdx.x * blockDim.x + threadIdx.x;
    if (i < n) {
        float x = v[i];
        x = x > 0.0f ? x : 0.0f;
        g[i] = x * tp[ntype[i]];
    }
}

// grid = nblk, 1024 threads. Fully self-contained bucket binning of one
// 16K-edge chunk into this block's private slice sorted[blk*EPB ...].
// lpref_g row: nb+1 entries (exclusive starts + total count).
__global__ __launch_bounds__(1024, 8)
void scatter_kernel(const int* __restrict__ src,
                    const int* __restrict__ dst,
                    const float* __restrict__ w,
                    const float* __restrict__ g,
                    unsigned* __restrict__ sorted,
                    unsigned* __restrict__ lpref_g,
                    int G, int n_edges, int nblk, int nb) {
    __shared__ unsigned stage[EPB];      // 64 KB
    __shared__ unsigned lstart[NBMAX];   // exclusive starts (4 KB)
    __shared__ unsigned lcur[NBMAX];     // working cursors   (4 KB)
    int blk = blockIdx.x, tid = threadIdx.x;
    bool last = (blk == nblk - 1);

    lcur[tid] = 0;                       // NBMAX == blockDim
    __syncthreads();

    const int4*   s4 = (const int4*)src;
    const int4*   d4 = (const int4*)dst;
    const float4* w4 = (const float4*)w;
    int gstart = blk * GPB;
    int gend = gstart + GPB; if (gend > G) gend = G;

    // pass 1: local histogram over this block's dst chunk (64 KB)
    for (int i = gstart + tid; i < gend; i += 1024) {
        int4 d = d4[i];
        atomicAdd(&lcur[((unsigned)d.x) >> BSHIFT], 1u);
        atomicAdd(&lcur[((unsigned)d.y) >> BSHIFT], 1u);
        atomicAdd(&lcur[((unsigned)d.z) >> BSHIFT], 1u);
        atomicAdd(&lcur[((unsigned)d.w) >> BSHIFT], 1u);
    }
    if (last) {
        for (int i = G * 4 + tid; i < n_edges; i += 1024)
            atomicAdd(&lcur[((unsigned)dst[i]) >> BSHIFT], 1u);
    }
    __syncthreads();

    // local exclusive scan (Hillis-Steele over 1024 entries in lstart)
    unsigned cntv = lcur[tid];
    lstart[tid] = cntv;
    __syncthreads();
    for (int o = 1; o < 1024; o <<= 1) {
        unsigned t = (tid >= o) ? lstart[tid - o] : 0u;
        __syncthreads();
        lstart[tid] += t;
        __syncthreads();
    }
    unsigned excl = lstart[tid] - cntv;
    lstart[tid] = excl;                  // own-slot rewrite, no race
    lcur[tid] = excl;
    __syncthreads();

    // pass 2: bin packed records (value mantissa-high | local dst) into LDS.
    // dst chunk re-read is L2-resident (64 KB x 2 blocks/CU).
    for (int i = gstart + tid; i < gend; i += 1024) {
        int4 s = s4[i]; int4 d = d4[i]; float4 wv = w4[i];
        {
            unsigned b = ((unsigned)d.x) >> BSHIFT;
            unsigned pos = atomicAdd(&lcur[b], 1u);
            stage[pos] = (__float_as_uint(wv.x * g[s.x]) & ~(unsigned)(BSIZE - 1)) |
                         ((unsigned)d.x & (BSIZE - 1));
        }
        {
            unsigned b = ((unsigned)d.y) >> BSHIFT;
            unsigned pos = atomicAdd(&lcur[b], 1u);
            stage[pos] = (__float_as_uint(wv.y * g[s.y]) & ~(unsigned)(BSIZE - 1)) |
                         ((unsigned)d.y & (BSIZE - 1));
        }
        {
            unsigned b = ((unsigned)d.z) >> BSHIFT;
            unsigned pos = atomicAdd(&lcur[b], 1u);
            stage[pos] = (__float_as_uint(wv.z * g[s.z]) & ~(unsigned)(BSIZE - 1)) |
                         ((unsigned)d.z & (BSIZE - 1));
        }
        {
            unsigned b = ((unsigned)d.w) >> BSHIFT;
            unsigned pos = atomicAdd(&lcur[b], 1u);
            stage[pos] = (__float_as_uint(wv.w * g[s.w]) & ~(unsigned)(BSIZE - 1)) |
                         ((unsigned)d.w & (BSIZE - 1));
        }
    }
    if (last) {
        for (int i = G * 4 + tid; i < n_edges; i += 1024) {
            int dd = dst[i];
            unsigned b = ((unsigned)dd) >> BSHIFT;
            unsigned pos = atomicAdd(&lcur[b], 1u);
            stage[pos] = (__float_as_uint(w[i] * g[src[i]]) & ~(unsigned)(BSIZE - 1)) |
                         ((unsigned)dd & (BSIZE - 1));
        }
    }
    __syncthreads();

    // dense contiguous copy-out of the whole stage buffer (uint4)
    unsigned count = (unsigned)(gend - gstart) * 4u +
                     (last ? (unsigned)(n_edges - G * 4) : 0u);
    uint4* out4 = (uint4*)(sorted + (size_t)blk * EPB);
    const uint4* st4 = (const uint4*)stage;
    unsigned nq = (count + 3u) >> 2;
    for (unsigned i = tid; i < nq; i += 1024) out4[i] = st4[i];

    // local-prefix row: nb exclusive starts + total count
    unsigned* row = lpref_g + (size_t)blk * (nb + 1);
    if (tid < (unsigned)nb)       row[tid] = lstart[tid];
    else if (tid == (unsigned)nb) row[nb]  = count;
}

// grid = nb, 512 threads; bucket b gathers its segment from every block's
// private slice (lpref matrix is L2/L3-resident), accumulates in LDS.
__global__ void accum_kernel(const unsigned* __restrict__ sorted,
                             const unsigned* __restrict__ lpref_g,
                             const float* __restrict__ v,
                             const float* __restrict__ stim,
                             const float* __restrict__ vrest,
                             const float* __restrict__ tau,
                             float* __restrict__ out,
                             int n_nodes, int nblk, int nb) {
    __shared__ float acc[BSIZE];
    int b = blockIdx.x, tid = threadIdx.x;
    acc[tid] = 0.0f;
    __syncthreads();
    for (int blk = tid; blk < nblk; blk += 512) {
        const unsigned* row = lpref_g + (size_t)blk * (nb + 1) + b;
        unsigned s = row[0], e = row[1];
        const unsigned* seg = sorted + (size_t)blk * EPB;
        for (unsigned j = s; j < e; j++) {
            unsigned u = seg[j];
            atomicAdd(&acc[u & (BSIZE - 1)],
                      __uint_as_float(u & ~(unsigned)(BSIZE - 1)));
        }
    }
    __syncthreads();
    int i = (b << BSHIFT) + tid;
    if (i < n_nodes)
        out[i] = (-v[i] + acc[tid] + stim[i] + vrest[i]) / tau[i];
}

// ---------------- fallback (agent-scope atomics, always correct) ----------------

__global__ void node_pre_kernel(const float* __restrict__ v,
                                const int* __restrict__ ntype,
                                const float* __restrict__ tp,
                                float* __restrict__ g,
                                float* __restrict__ msg, int n) {
    int i = blockIdx.x * blockDim.x + threadIdx.x;
    if (i < n) {
        float x = v[i];
        x = x > 0.0f ? x : 0.0f;
        g[i] = x * tp[ntype[i]];
        msg[i] = 0.0f;
    }
}

__global__ void edge_scatter_kernel(const int* __restrict__ src,
                                    const int* __restrict__ dst,
                                    const float* __restrict__ w,
                                    const float* __restrict__ g,
                                    float* __restrict__ msg, int n_vec) {
    int i = blockIdx.x * blockDim.x + threadIdx.x;
    if (i < n_vec) {
        int4 s = ((const int4*)src)[i];
        int4 d = ((const int4*)dst)[i];
        float4 wv = ((const float4*)w)[i];
        atomicAdd(&msg[d.x], wv.x * g[s.x]);
        atomicAdd(&msg[d.y], wv.y * g[s.y]);
        atomicAdd(&msg[d.z], wv.z * g[s.z]);
        atomicAdd(&msg[d.w], wv.w * g[s.w]);
    }
}

__global__ void edge_scatter_tail(const int* __restrict__ src,
                                  const int* __restrict__ dst,
                                  const float* __restrict__ w,
                                  const float* __restrict__ g,
                                  float* __restrict__ msg,
                                  int start, int n_edges) {
    int i = start + blockIdx.x * blockDim.x + threadIdx.x;
    if (i < n_edges) atomicAdd(&msg[dst[i]], w[i] * g[src[i]]);
}

__global__ void node_post_kernel(const float* __restrict__ v,
                                 const float* __restrict__ msg,
                                 const float* __restrict__ stim,
                                 const float* __restrict__ vrest,
                                 const float* __restrict__ tau,
                                 float* __restrict__ out, int n) {
    int i = blockIdx.x * blockDim.x + threadIdx.x;
    if (i < n)
        out[i] = (-v[i] + msg[i] + stim[i] + vrest[i]) / tau[i];
}

// ---------------- launch ----------------

extern "C" void kernel_launch(void* const* d_in, const int* in_sizes, int n_in,
                              void* d_out, int out_size, void* d_ws, size_t ws_size,
                              hipStream_t stream) {
    const float* voltage  = (const float*)d_in[0];
    const float* stimulus = (const float*)d_in[1];
    const int*   ntype    = (const int*)d_in[2];
    const int*   edge_idx = (const int*)d_in[3];
    const float* w        = (const float*)d_in[4];
    const float* vrest    = (const float*)d_in[5];
    const float* tau      = (const float*)d_in[6];
    const float* tp       = (const float*)d_in[7];
    float* out = (float*)d_out;

    const int n_nodes = in_sizes[0];
    const int n_edges = in_sizes[4];
    const int* src = edge_idx;
    const int* dst = edge_idx + n_edges;

    const int B = 256;
    const int G = n_edges / 4;
    int nblk = (G + GPB - 1) / GPB;
    if (nblk < 1) nblk = 1;
    const int nb = (n_nodes + BSIZE - 1) / BSIZE;

    auto align256 = [](size_t x) { return (x + 255) & ~(size_t)255; };
    size_t g_off      = 0;
    size_t sorted_off = align256(g_off + (size_t)n_nodes * 4);
    size_t lpref_off  = align256(sorted_off + (size_t)nblk * EPB * 4);
    size_t need       = align256(lpref_off + (size_t)nblk * (nb + 1) * 4);

    if (nb < NBMAX && ws_size >= need) {
        float*    g      = (float*)((char*)d_ws + g_off);
        unsigned* sorted = (unsigned*)((char*)d_ws + sorted_off);
        unsigned* lpref  = (unsigned*)((char*)d_ws + lpref_off);

        pre_g_kernel<<<(n_nodes + B - 1) / B, B, 0, stream>>>(
            voltage, ntype, tp, g, n_nodes);
        scatter_kernel<<<nblk, 1024, 0, stream>>>(
            src, dst, w, g, sorted, lpref, G, n_edges, nblk, nb);
        accum_kernel<<<nb, 512, 0, stream>>>(
            sorted, lpref, voltage, stimulus, vrest, tau, out,
            n_nodes, nblk, nb);
    } else {
        float* g   = (float*)d_ws;
        float* msg = (float*)d_ws + n_nodes;
        node_pre_kernel<<<(n_nodes + B - 1) / B, B, 0, stream>>>(
            voltage, ntype, tp, g, msg, n_nodes);
        if (G > 0)
            edge_scatter_kernel<<<(G + B - 1) / B, B, 0, stream>>>(
                src, dst, w, g, msg, G);
        if (G * 4 < n_edges) {
            int rem = n_edges - G * 4;
            edge_scatter_tail<<<(rem + B - 1) / B, B, 0, stream>>>(
                src, dst, w, g, msg, G * 4, n_edges);
        }
        node_post_kernel<<<(n_nodes + B - 1) / B, B, 0, stream>>>(
            voltage, msg, stimulus, vrest, tau, out, n_nodes);
    }
}

// Round 7
// 420.356 us; speedup vs baseline: 1.2309x; 1.2309x over previous
//
#include <hip/hip_runtime.h>

// dv = (-v + segment_sum(w * relu(v[src]) * tp[ntype[src]], dst) + stim + Vrest) / tau
// N_NODES = 500000, N_EDGES = 16000000. edge_index flat: src=[0,E), dst=[E,2E).
//
// R1: agent-scope fp32 atomics -> memory-side RMW wall (~20G/s) -> 785us.
// R2: counting sort, direct 4B random writes -> 7x write amp -> 489us scatter.
// R3: workgroup-scope atomics == agent-scope on gfx950 (no relocation).
// R4: LDS-staged bucket sort + coalesced bursts -> 241us scatter @ 19% occ.
// R5: 1024-thr scatter + prefix-derived hist -> 188us scatter, 286us scaffolding.
// R6: per-block private slices (no global sort) -> accum read one segment per
//     THREAD serially: 64 lines/wave-instr, L2 thrash, 641MB fetch (10x), 212us.
// R7 (this): accum reads one segment per WAVE (coalesced, line consumed
//     immediately); scatter keeps dst in registers across both passes
//     (dst read once from HBM, no pass-2 re-read).

#define BSHIFT 9
#define BSIZE  512               // nodes per bucket
#define NBMAX  1024              // > nb = ceil(500000/512) = 977
#define GPB    4096              // int4 groups per scatter block = 16384 edges
#define EPB    (GPB * 4)

// ---------------- main path ----------------

__global__ void pre_g_kernel(const float* __restrict__ v,
                             const int* __restrict__ ntype,
                             const float* __restrict__ tp,
                             float* __restrict__ g, int n) {
    int i = blockIdx.x * blockDim.x + threadIdx.x;
    if (i < n) {
        float x = v[i];
        x = x > 0.0f ? x : 0.0f;
        g[i] = x * tp[ntype[i]];
    }
}

// grid = nblk, 1024 threads. Self-contained bucket binning of one 16K-edge
// chunk into this block's private slice sorted[blk*EPB ...]. dst values are
// held in registers across pass1 (hist) and pass2 (bin) -> read once.
__global__ __launch_bounds__(1024, 8)
void scatter_kernel(const int* __restrict__ src,
                    const int* __restrict__ dst,
                    const float* __restrict__ w,
                    const float* __restrict__ g,
                    unsigned* __restrict__ sorted,
                    unsigned* __restrict__ lpref_g,
                    int G, int n_edges, int nblk, int nb) {
    __shared__ unsigned stage[EPB];      // 64 KB
    __shared__ unsigned lstart[NBMAX];   // exclusive starts (4 KB)
    __shared__ unsigned lcur[NBMAX];     // working cursors   (4 KB)
    int blk = blockIdx.x, tid = threadIdx.x;
    bool last = (blk == nblk - 1);

    lcur[tid] = 0;                       // NBMAX == blockDim
    __syncthreads();

    const int4*   s4 = (const int4*)src;
    const int4*   d4 = (const int4*)dst;
    const float4* w4 = (const float4*)w;
    int gstart = blk * GPB;
    int gend = gstart + GPB; if (gend > G) gend = G;

    // pass 1: load dst groups into registers + local histogram
    int4 dreg[4];
    #pragma unroll
    for (int k = 0; k < 4; k++) {
        int i = gstart + tid + k * 1024;
        if (i < gend) {
            int4 d = d4[i];
            dreg[k] = d;
            atomicAdd(&lcur[((unsigned)d.x) >> BSHIFT], 1u);
            atomicAdd(&lcur[((unsigned)d.y) >> BSHIFT], 1u);
            atomicAdd(&lcur[((unsigned)d.z) >> BSHIFT], 1u);
            atomicAdd(&lcur[((unsigned)d.w) >> BSHIFT], 1u);
        }
    }
    if (last) {
        for (int i = G * 4 + tid; i < n_edges; i += 1024)
            atomicAdd(&lcur[((unsigned)dst[i]) >> BSHIFT], 1u);
    }
    __syncthreads();

    // local exclusive scan (Hillis-Steele over 1024 entries)
    unsigned cntv = lcur[tid];
    lstart[tid] = cntv;
    __syncthreads();
    for (int o = 1; o < 1024; o <<= 1) {
        unsigned t = (tid >= o) ? lstart[tid - o] : 0u;
        __syncthreads();
        lstart[tid] += t;
        __syncthreads();
    }
    unsigned excl = lstart[tid] - cntv;
    lstart[tid] = excl;                  // own-slot rewrite, no race
    lcur[tid] = excl;
    __syncthreads();

    // pass 2: bin packed records (value mantissa-high | local dst) into LDS,
    // dst from registers; src/w streamed (first read).
    #pragma unroll
    for (int k = 0; k < 4; k++) {
        int i = gstart + tid + k * 1024;
        if (i < gend) {
            int4 s = s4[i]; float4 wv = w4[i]; int4 d = dreg[k];
            {
                unsigned b = ((unsigned)d.x) >> BSHIFT;
                unsigned pos = atomicAdd(&lcur[b], 1u);
                stage[pos] = (__float_as_uint(wv.x * g[s.x]) & ~(unsigned)(BSIZE - 1)) |
                             ((unsigned)d.x & (BSIZE - 1));
            }
            {
                unsigned b = ((unsigned)d.y) >> BSHIFT;
                unsigned pos = atomicAdd(&lcur[b], 1u);
                stage[pos] = (__float_as_uint(wv.y * g[s.y]) & ~(unsigned)(BSIZE - 1)) |
                             ((unsigned)d.y & (BSIZE - 1));
            }
            {
                unsigned b = ((unsigned)d.z) >> BSHIFT;
                unsigned pos = atomicAdd(&lcur[b], 1u);
                stage[pos] = (__float_as_uint(wv.z * g[s.z]) & ~(unsigned)(BSIZE - 1)) |
                             ((unsigned)d.z & (BSIZE - 1));
            }
            {
                unsigned b = ((unsigned)d.w) >> BSHIFT;
                unsigned pos = atomicAdd(&lcur[b], 1u);
                stage[pos] = (__float_as_uint(wv.w * g[s.w]) & ~(unsigned)(BSIZE - 1)) |
                             ((unsigned)d.w & (BSIZE - 1));
            }
        }
    }
    if (last) {
        for (int i = G * 4 + tid; i < n_edges; i += 1024) {
            int dd = dst[i];
            unsigned b = ((unsigned)dd) >> BSHIFT;
            unsigned pos = atomicAdd(&lcur[b], 1u);
            stage[pos] = (__float_as_uint(w[i] * g[src[i]]) & ~(unsigned)(BSIZE - 1)) |
                         ((unsigned)dd & (BSIZE - 1));
        }
    }
    __syncthreads();

    // dense contiguous copy-out of the whole stage buffer (uint4)
    unsigned count = (unsigned)(gend > gstart ? (gend - gstart) * 4 : 0) +
                     (last ? (unsigned)(n_edges - G * 4) : 0u);
    uint4* out4 = (uint4*)(sorted + (size_t)blk * EPB);
    const uint4* st4 = (const uint4*)stage;
    unsigned nq = (count + 3u) >> 2;
    for (unsigned i = tid; i < nq; i += 1024) out4[i] = st4[i];

    // local-prefix row: nb exclusive starts + total count
    unsigned* row = lpref_g + (size_t)blk * (nb + 1);
    if (tid < (unsigned)nb)       row[tid] = lstart[tid];
    else if (tid == (unsigned)nb) row[nb]  = count;
}

// grid = nb, 512 threads (8 waves). Wave handles one (slice, bucket) segment
// at a time: lanes read consecutive records -> coalesced, line consumed
// immediately (kills R6's 10x over-fetch).
__global__ void accum_kernel(const unsigned* __restrict__ sorted,
                             const unsigned* __restrict__ lpref_g,
                             const float* __restrict__ v,
                             const float* __restrict__ stim,
                             const float* __restrict__ vrest,
                             const float* __restrict__ tau,
                             float* __restrict__ out,
                             int n_nodes, int nblk, int nb) {
    __shared__ float acc[BSIZE];
    int b = blockIdx.x, tid = threadIdx.x;
    acc[tid] = 0.0f;
    __syncthreads();
    int wave = tid >> 6, lane = tid & 63;
    for (int blk = wave; blk < nblk; blk += 8) {
        const unsigned* row = lpref_g + (size_t)blk * (nb + 1) + b;
        unsigned s = row[0], e = row[1];          // wave-broadcast loads
        const unsigned* seg = sorted + (size_t)blk * EPB;
        for (unsigned j = s + lane; j < e; j += 64) {
            unsigned u = seg[j];
            atomicAdd(&acc[u & (BSIZE - 1)],
                      __uint_as_float(u & ~(unsigned)(BSIZE - 1)));
        }
    }
    __syncthreads();
    int i = (b << BSHIFT) + tid;
    if (i < n_nodes)
        out[i] = (-v[i] + acc[tid] + stim[i] + vrest[i]) / tau[i];
}

// ---------------- fallback (agent-scope atomics, always correct) ----------------

__global__ void node_pre_kernel(const float* __restrict__ v,
                                const int* __restrict__ ntype,
                                const float* __restrict__ tp,
                                float* __restrict__ g,
                                float* __restrict__ msg, int n) {
    int i = blockIdx.x * blockDim.x + threadIdx.x;
    if (i < n) {
        float x = v[i];
        x = x > 0.0f ? x : 0.0f;
        g[i] = x * tp[ntype[i]];
        msg[i] = 0.0f;
    }
}

__global__ void edge_scatter_kernel(const int* __restrict__ src,
                                    const int* __restrict__ dst,
                                    const float* __restrict__ w,
                                    const float* __restrict__ g,
                                    float* __restrict__ msg, int n_vec) {
    int i = blockIdx.x * blockDim.x + threadIdx.x;
    if (i < n_vec) {
        int4 s = ((const int4*)src)[i];
        int4 d = ((const int4*)dst)[i];
        float4 wv = ((const float4*)w)[i];
        atomicAdd(&msg[d.x], wv.x * g[s.x]);
        atomicAdd(&msg[d.y], wv.y * g[s.y]);
        atomicAdd(&msg[d.z], wv.z * g[s.z]);
        atomicAdd(&msg[d.w], wv.w * g[s.w]);
    }
}

__global__ void edge_scatter_tail(const int* __restrict__ src,
                                  const int* __restrict__ dst,
                                  const float* __restrict__ w,
                                  const float* __restrict__ g,
                                  float* __restrict__ msg,
                                  int start, int n_edges) {
    int i = start + blockIdx.x * blockDim.x + threadIdx.x;
    if (i < n_edges) atomicAdd(&msg[dst[i]], w[i] * g[src[i]]);
}

__global__ void node_post_kernel(const float* __restrict__ v,
                                 const float* __restrict__ msg,
                                 const float* __restrict__ stim,
                                 const float* __restrict__ vrest,
                                 const float* __restrict__ tau,
                                 float* __restrict__ out, int n) {
    int i = blockIdx.x * blockDim.x + threadIdx.x;
    if (i < n)
        out[i] = (-v[i] + msg[i] + stim[i] + vrest[i]) / tau[i];
}

// ---------------- launch ----------------

extern "C" void kernel_launch(void* const* d_in, const int* in_sizes, int n_in,
                              void* d_out, int out_size, void* d_ws, size_t ws_size,
                              hipStream_t stream) {
    const float* voltage  = (const float*)d_in[0];
    const float* stimulus = (const float*)d_in[1];
    const int*   ntype    = (const int*)d_in[2];
    const int*   edge_idx = (const int*)d_in[3];
    const float* w        = (const float*)d_in[4];
    const float* vrest    = (const float*)d_in[5];
    const float* tau      = (const float*)d_in[6];
    const float* tp       = (const float*)d_in[7];
    float* out = (float*)d_out;

    const int n_nodes = in_sizes[0];
    const int n_edges = in_sizes[4];
    const int* src = edge_idx;
    const int* dst = edge_idx + n_edges;

    const int B = 256;
    const int G = n_edges / 4;
    int nblk = (G + GPB - 1) / GPB;
    if (nblk < 1) nblk = 1;
    const int nb = (n_nodes + BSIZE - 1) / BSIZE;

    auto align256 = [](size_t x) { return (x + 255) & ~(size_t)255; };
    size_t g_off      = 0;
    size_t sorted_off = align256(g_off + (size_t)n_nodes * 4);
    size_t lpref_off  = align256(sorted_off + (size_t)nblk * EPB * 4);
    size_t need       = align256(lpref_off + (size_t)nblk * (nb + 1) * 4);

    if (nb < NBMAX && ws_size >= need) {
        float*    g      = (float*)((char*)d_ws + g_off);
        unsigned* sorted = (unsigned*)((char*)d_ws + sorted_off);
        unsigned* lpref  = (unsigned*)((char*)d_ws + lpref_off);

        pre_g_kernel<<<(n_nodes + B - 1) / B, B, 0, stream>>>(
            voltage, ntype, tp, g, n_nodes);
        scatter_kernel<<<nblk, 1024, 0, stream>>>(
            src, dst, w, g, sorted, lpref, G, n_edges, nblk, nb);
        accum_kernel<<<nb, 512, 0, stream>>>(
            sorted, lpref, voltage, stimulus, vrest, tau, out,
            n_nodes, nblk, nb);
    } else {
        float* g   = (float*)d_ws;
        float* msg = (float*)d_ws + n_nodes;
        node_pre_kernel<<<(n_nodes + B - 1) / B, B, 0, stream>>>(
            voltage, ntype, tp, g, msg, n_nodes);
        if (G > 0)
            edge_scatter_kernel<<<(G + B - 1) / B, B, 0, stream>>>(
                src, dst, w, g, msg, G);
        if (G * 4 < n_edges) {
            int rem = n_edges - G * 4;
            edge_scatter_tail<<<(rem + B - 1) / B, B, 0, stream>>>(
                src, dst, w, g, msg, G * 4, n_edges);
        }
        node_post_kernel<<<(n_nodes + B - 1) / B, B, 0, stream>>>(
            voltage, msg, stimulus, vrest, tau, out, n_nodes);
    }
}

// Round 8
// 419.181 us; speedup vs baseline: 1.2344x; 1.0028x over previous
//
#include <hip/hip_runtime.h>

// dv = (-v + segment_sum(w * relu(v[src]) * tp[ntype[src]], dst) + stim + Vrest) / tau
// N_NODES = 500000, N_EDGES = 16000000. edge_index flat: src=[0,E), dst=[E,2E).
//
// R1: agent-scope fp32 atomics -> memory-side RMW wall (~20G/s) -> 785us.
// R2: counting sort, direct 4B random writes -> 7x write amp -> 489us scatter.
// R3: workgroup-scope atomics == agent-scope on gfx950 (no relocation).
// R4: LDS-staged bucket sort + coalesced bursts -> 241us scatter @ 19% occ.
// R5: 1024-thr scatter + prefix-derived hist -> 188us scatter.
// R6: per-block private slices -> accum thread-serial segments: L2 thrash 10x.
// R7: wave-per-segment accum + dst-in-regs scatter -> 420us total; scatter
//     latency-bound (20-barrier scan), accum (s,e)->seg dependent chains and
//     27% lane utilization (16.8-record segments).
// R8 (this): 1024-node buckets (nb=489, 33.5-rec segments, 1.9MB lpref);
//     accum prefetches 64 (s,e) pairs per wave then shfl-broadcasts (no
//     serial chain); scatter scan via shfl (3 barriers). 10-bit dst steal.

#define BSHIFT 10
#define BSIZE  1024              // nodes per bucket
#define NBMAX  512               // > nb = ceil(500000/1024) = 489
#define GPB    4096              // int4 groups per scatter block = 16384 edges
#define EPB    (GPB * 4)

// ---------------- main path ----------------

__global__ void pre_g_kernel(const float* __restrict__ v,
                             const int* __restrict__ ntype,
                             const float* __restrict__ tp,
                             float* __restrict__ g, int n) {
    int i = blockIdx.x * blockDim.x + threadIdx.x;
    if (i < n) {
        float x = v[i];
        x = x > 0.0f ? x : 0.0f;
        g[i] = x * tp[ntype[i]];
    }
}

// grid = nblk, 1024 threads. Self-contained bucket binning of one 16K-edge
// chunk into this block's private slice sorted[blk*EPB ...]. dst in registers
// across both passes; scan via shfl (3 barriers).
__global__ __launch_bounds__(1024, 8)
void scatter_kernel(const int* __restrict__ src,
                    const int* __restrict__ dst,
                    const float* __restrict__ w,
                    const float* __restrict__ g,
                    unsigned* __restrict__ sorted,
                    unsigned* __restrict__ lpref_g,
                    int G, int n_edges, int nblk, int nb) {
    __shared__ unsigned stage[EPB];      // 64 KB
    __shared__ unsigned lstart[NBMAX];   // exclusive starts (2 KB)
    __shared__ unsigned lcur[NBMAX];     // working cursors   (2 KB)
    __shared__ unsigned wsum[16];
    int blk = blockIdx.x, tid = threadIdx.x;
    int wid = tid >> 6, lane = tid & 63;
    bool last = (blk == nblk - 1);

    if (tid < NBMAX) lcur[tid] = 0;
    __syncthreads();

    const int4*   s4 = (const int4*)src;
    const int4*   d4 = (const int4*)dst;
    const float4* w4 = (const float4*)w;
    int gstart = blk * GPB;
    int gend = gstart + GPB; if (gend > G) gend = G;

    // pass 1: load dst groups into registers + local histogram
    int4 dreg[4];
    #pragma unroll
    for (int k = 0; k < 4; k++) {
        int i = gstart + tid + k * 1024;
        if (i < gend) {
            int4 d = d4[i];
            dreg[k] = d;
            atomicAdd(&lcur[((unsigned)d.x) >> BSHIFT], 1u);
            atomicAdd(&lcur[((unsigned)d.y) >> BSHIFT], 1u);
            atomicAdd(&lcur[((unsigned)d.z) >> BSHIFT], 1u);
            atomicAdd(&lcur[((unsigned)d.w) >> BSHIFT], 1u);
        }
    }
    if (last) {
        for (int i = G * 4 + tid; i < n_edges; i += 1024)
            atomicAdd(&lcur[((unsigned)dst[i]) >> BSHIFT], 1u);
    }
    __syncthreads();

    // exclusive scan over NBMAX=512 entries (first 8 waves hold counts):
    // wave-level shfl scan + cross-wave scan of 8 partials.
    unsigned cntv = (tid < NBMAX) ? lcur[tid] : 0u;
    unsigned inc = cntv;
    #pragma unroll
    for (int o = 1; o < 64; o <<= 1) {
        unsigned t = __shfl_up(inc, o, 64);
        if (lane >= o) inc += t;
    }
    if (lane == 63) wsum[wid] = inc;
    __syncthreads();
    if (tid < 64) {
        unsigned x = (lane < 16) ? wsum[lane] : 0u;
        unsigned xi = x;
        #pragma unroll
        for (int o = 1; o < 16; o <<= 1) {
            unsigned t = __shfl_up(xi, o, 64);
            if (lane >= o) xi += t;
        }
        if (lane < 16) wsum[lane] = xi - x;   // exclusive wave offsets
    }
    __syncthreads();
    if (tid < NBMAX) {
        unsigned excl = inc - cntv + wsum[wid];
        lstart[tid] = excl;
        lcur[tid] = excl;
    }
    __syncthreads();

    // pass 2: bin packed records (value top-22 bits | 10-bit local dst)
    #pragma unroll
    for (int k = 0; k < 4; k++) {
        int i = gstart + tid + k * 1024;
        if (i < gend) {
            int4 s = s4[i]; float4 wv = w4[i]; int4 d = dreg[k];
            {
                unsigned b = ((unsigned)d.x) >> BSHIFT;
                unsigned pos = atomicAdd(&lcur[b], 1u);
                stage[pos] = (__float_as_uint(wv.x * g[s.x]) & ~(unsigned)(BSIZE - 1)) |
                             ((unsigned)d.x & (BSIZE - 1));
            }
            {
                unsigned b = ((unsigned)d.y) >> BSHIFT;
                unsigned pos = atomicAdd(&lcur[b], 1u);
                stage[pos] = (__float_as_uint(wv.y * g[s.y]) & ~(unsigned)(BSIZE - 1)) |
                             ((unsigned)d.y & (BSIZE - 1));
            }
            {
                unsigned b = ((unsigned)d.z) >> BSHIFT;
                unsigned pos = atomicAdd(&lcur[b], 1u);
                stage[pos] = (__float_as_uint(wv.z * g[s.z]) & ~(unsigned)(BSIZE - 1)) |
                             ((unsigned)d.z & (BSIZE - 1));
            }
            {
                unsigned b = ((unsigned)d.w) >> BSHIFT;
                unsigned pos = atomicAdd(&lcur[b], 1u);
                stage[pos] = (__float_as_uint(wv.w * g[s.w]) & ~(unsigned)(BSIZE - 1)) |
                             ((unsigned)d.w & (BSIZE - 1));
            }
        }
    }
    if (last) {
        for (int i = G * 4 + tid; i < n_edges; i += 1024) {
            int dd = dst[i];
            unsigned b = ((unsigned)dd) >> BSHIFT;
            unsigned pos = atomicAdd(&lcur[b], 1u);
            stage[pos] = (__float_as_uint(w[i] * g[src[i]]) & ~(unsigned)(BSIZE - 1)) |
                         ((unsigned)dd & (BSIZE - 1));
        }
    }
    __syncthreads();

    // dense contiguous copy-out of the whole stage buffer (uint4)
    unsigned count = (unsigned)(gend > gstart ? (gend - gstart) * 4 : 0) +
                     (last ? (unsigned)(n_edges - G * 4) : 0u);
    uint4* out4 = (uint4*)(sorted + (size_t)blk * EPB);
    const uint4* st4 = (const uint4*)stage;
    unsigned nq = (count + 3u) >> 2;
    for (unsigned i = tid; i < nq; i += 1024) out4[i] = st4[i];

    // local-prefix row: nb exclusive starts + total count
    unsigned* row = lpref_g + (size_t)blk * (nb + 1);
    if (tid < (unsigned)nb)       row[tid] = lstart[tid];
    else if (tid == (unsigned)nb) row[nb]  = count;
}

// grid = nb, 512 threads (8 waves). Each wave prefetches (s,e) for 64 slices
// into registers (independent in-flight loads), then shfl-broadcasts each and
// reads that slice's segment coalesced.
__global__ __launch_bounds__(512, 8)
void accum_kernel(const unsigned* __restrict__ sorted,
                  const unsigned* __restrict__ lpref_g,
                  const float* __restrict__ v,
                  const float* __restrict__ stim,
                  const float* __restrict__ vrest,
                  const float* __restrict__ tau,
                  float* __restrict__ out,
                  int n_nodes, int nblk, int nb) {
    __shared__ float acc[BSIZE];
    int b = blockIdx.x, tid = threadIdx.x;
    acc[tid] = 0.0f;
    acc[tid + 512] = 0.0f;
    __syncthreads();
    int wave = tid >> 6, lane = tid & 63;
    int rowlen = nb + 1;
    for (int base = wave * 64; base < nblk; base += 8 * 64) {
        int myslice = base + lane;
        unsigned s = 0, e = 0;
        if (myslice < nblk) {
            const unsigned* row = lpref_g + (size_t)myslice * rowlen + b;
            s = row[0];
            e = row[1];
        }
        int kmax = nblk - base; if (kmax > 64) kmax = 64;
        for (int k = 0; k < kmax; k++) {
            unsigned sv = __shfl(s, k, 64);
            unsigned ev = __shfl(e, k, 64);
            const unsigned* seg = sorted + (size_t)(base + k) * EPB;
            for (unsigned j = sv + lane; j < ev; j += 64) {
                unsigned u = seg[j];
                atomicAdd(&acc[u & (BSIZE - 1)],
                          __uint_as_float(u & ~(unsigned)(BSIZE - 1)));
            }
        }
    }
    __syncthreads();
    int i0 = (b << BSHIFT) + tid;
    if (i0 < n_nodes)
        out[i0] = (-v[i0] + acc[tid] + stim[i0] + vrest[i0]) / tau[i0];
    int i1 = i0 + 512;
    if (i1 < n_nodes)
        out[i1] = (-v[i1] + acc[tid + 512] + stim[i1] + vrest[i1]) / tau[i1];
}

// ---------------- fallback (agent-scope atomics, always correct) ----------------

__global__ void node_pre_kernel(const float* __restrict__ v,
                                const int* __restrict__ ntype,
                                const float* __restrict__ tp,
                                float* __restrict__ g,
                                float* __restrict__ msg, int n) {
    int i = blockIdx.x * blockDim.x + threadIdx.x;
    if (i < n) {
        float x = v[i];
        x = x > 0.0f ? x : 0.0f;
        g[i] = x * tp[ntype[i]];
        msg[i] = 0.0f;
    }
}

__global__ void edge_scatter_kernel(const int* __restrict__ src,
                                    const int* __restrict__ dst,
                                    const float* __restrict__ w,
                                    const float* __restrict__ g,
                                    float* __restrict__ msg, int n_vec) {
    int i = blockIdx.x * blockDim.x + threadIdx.x;
    if (i < n_vec) {
        int4 s = ((const int4*)src)[i];
        int4 d = ((const int4*)dst)[i];
        float4 wv = ((const float4*)w)[i];
        atomicAdd(&msg[d.x], wv.x * g[s.x]);
        atomicAdd(&msg[d.y], wv.y * g[s.y]);
        atomicAdd(&msg[d.z], wv.z * g[s.z]);
        atomicAdd(&msg[d.w], wv.w * g[s.w]);
    }
}

__global__ void edge_scatter_tail(const int* __restrict__ src,
                                  const int* __restrict__ dst,
                                  const float* __restrict__ w,
                                  const float* __restrict__ g,
                                  float* __restrict__ msg,
                                  int start, int n_edges) {
    int i = start + blockIdx.x * blockDim.x + threadIdx.x;
    if (i < n_edges) atomicAdd(&msg[dst[i]], w[i] * g[src[i]]);
}

__global__ void node_post_kernel(const float* __restrict__ v,
                                 const float* __restrict__ msg,
                                 const float* __restrict__ stim,
                                 const float* __restrict__ vrest,
                                 const float* __restrict__ tau,
                                 float* __restrict__ out, int n) {
    int i = blockIdx.x * blockDim.x + threadIdx.x;
    if (i < n)
        out[i] = (-v[i] + msg[i] + stim[i] + vrest[i]) / tau[i];
}

// ---------------- launch ----------------

extern "C" void kernel_launch(void* const* d_in, const int* in_sizes, int n_in,
                              void* d_out, int out_size, void* d_ws, size_t ws_size,
                              hipStream_t stream) {
    const float* voltage  = (const float*)d_in[0];
    const float* stimulus = (const float*)d_in[1];
    const int*   ntype    = (const int*)d_in[2];
    const int*   edge_idx = (const int*)d_in[3];
    const float* w        = (const float*)d_in[4];
    const float* vrest    = (const float*)d_in[5];
    const float* tau      = (const float*)d_in[6];
    const float* tp       = (const float*)d_in[7];
    float* out = (float*)d_out;

    const int n_nodes = in_sizes[0];
    const int n_edges = in_sizes[4];
    const int* src = edge_idx;
    const int* dst = edge_idx + n_edges;

    const int B = 256;
    const int G = n_edges / 4;
    int nblk = (G + GPB - 1) / GPB;
    if (nblk < 1) nblk = 1;
    const int nb = (n_nodes + BSIZE - 1) / BSIZE;

    auto align256 = [](size_t x) { return (x + 255) & ~(size_t)255; };
    size_t g_off      = 0;
    size_t sorted_off = align256(g_off + (size_t)n_nodes * 4);
    size_t lpref_off  = align256(sorted_off + (size_t)nblk * EPB * 4);
    size_t need       = align256(lpref_off + (size_t)nblk * (nb + 1) * 4);

    if (nb < NBMAX && ws_size >= need) {
        float*    g      = (float*)((char*)d_ws + g_off);
        unsigned* sorted = (unsigned*)((char*)d_ws + sorted_off);
        unsigned* lpref  = (unsigned*)((char*)d_ws + lpref_off);

        pre_g_kernel<<<(n_nodes + B - 1) / B, B, 0, stream>>>(
            voltage, ntype, tp, g, n_nodes);
        scatter_kernel<<<nblk, 1024, 0, stream>>>(
            src, dst, w, g, sorted, lpref, G, n_edges, nblk, nb);
        accum_kernel<<<nb, 512, 0, stream>>>(
            sorted, lpref, voltage, stimulus, vrest, tau, out,
            n_nodes, nblk, nb);
    } else {
        float* g   = (float*)d_ws;
        float* msg = (float*)d_ws + n_nodes;
        node_pre_kernel<<<(n_nodes + B - 1) / B, B, 0, stream>>>(
            voltage, ntype, tp, g, msg, n_nodes);
        if (G > 0)
            edge_scatter_kernel<<<(G + B - 1) / B, B, 0, stream>>>(
                src, dst, w, g, msg, G);
        if (G * 4 < n_edges) {
            int rem = n_edges - G * 4;
            edge_scatter_tail<<<(rem + B - 1) / B, B, 0, stream>>>(
                src, dst, w, g, msg, G * 4, n_edges);
        }
        node_post_kernel<<<(n_nodes + B - 1) / B, B, 0, stream>>>(
            voltage, msg, stimulus, vrest, tau, out, n_nodes);
    }
}